// Round 2
// baseline (1796.630 us; speedup 1.0000x reference)
//
#include <hip/hip_runtime.h>
#include <hip/hip_bf16.h>
#include <cstdint>

// ---------------------------------------------------------------------------
// SquashedGaussianMoEActor forward, MI355X (gfx950).
// Split-f16 MFMA (hi/lo pairs, 3x v_mfma_f32_16x16x32_f16) for fp32-quality
// accuracy. Attention folded: score = t1*(eW2@K@q), vals = t1@(eW2@V).
// eo is never materialized. Workspace ~121 MB with explicit aliasing.
// B=8192, OBS=128, H=D=512, E=16, T=50, A=32.
// ---------------------------------------------------------------------------

typedef _Float16 f16;
typedef _Float16 f16x4 __attribute__((ext_vector_type(4)));
typedef _Float16 f16x8 __attribute__((ext_vector_type(8)));
typedef float f32x4 __attribute__((ext_vector_type(4)));

__device__ __forceinline__ void fsplit(float x, f16& h, f16& l) {
    h = (f16)x;
    l = (f16)(x - (float)h);
}

// --- elementwise fp32 -> f16 pair split -----------------------------------
__global__ void split_pairs(const float* __restrict__ x, f16* __restrict__ h,
                            f16* __restrict__ l, int n4) {
    int i = blockIdx.x * 256 + threadIdx.x;
    if (i >= n4) return;
    float4 v = ((const float4*)x)[i];
    float a[4] = {v.x, v.y, v.z, v.w};
    f16x4 hh, ll;
#pragma unroll
    for (int j = 0; j < 4; ++j) { f16 hj, lj; fsplit(a[j], hj, lj); hh[j] = hj; ll[j] = lj; }
    *(f16x4*)&h[(long)i * 4] = hh;
    *(f16x4*)&l[(long)i * 4] = ll;
}

// --- transpose [K,N] fp32 -> [N,K] f16 pairs (batched via z) ---------------
__global__ void transpose_split(const float* __restrict__ W, f16* __restrict__ Th,
                                f16* __restrict__ Tl, int K, int N, long ist, long ost) {
    __shared__ float t[32][33];
    const float* Wb = W + (long)blockIdx.z * ist;
    const int k0 = blockIdx.x * 32, n0 = blockIdx.y * 32;
    const int tid = threadIdx.x;
    const int r = tid >> 3, c4 = (tid & 7) * 4;
    float4 v = *(const float4*)&Wb[(long)(k0 + r) * N + n0 + c4];
    t[r][c4] = v.x; t[r][c4 + 1] = v.y; t[r][c4 + 2] = v.z; t[r][c4 + 3] = v.w;
    __syncthreads();
    f16x4 hh, ll;
#pragma unroll
    for (int j = 0; j < 4; ++j) { f16 hj, lj; fsplit(t[c4 + j][r], hj, lj); hh[j] = hj; ll[j] = lj; }
    long ob = (long)blockIdx.z * ost + (long)(n0 + r) * K + k0 + c4;
    *(f16x4*)&Th[ob] = hh;
    *(f16x4*)&Tl[ob] = ll;
}

// --- split-f16 GEMM: C = act(A @ B^T_stored + bias) ------------------------
// Tile 128x128, BK=64, 4 waves each owning 64x64 (4x4 frags of 16x16x32).
// OUTM: 0 pair write (+opt rowScale), 1 pair write transposed, 2 f32 write,
//       3 f32 accumulate, 4 score mode (row-dot with KQ2 -> atomicAdd).
template <int OUTM, bool RELU>
__global__ __launch_bounds__(256, 1) void gemm_pair(
    const f16* __restrict__ Ah, const f16* __restrict__ Al, int lda, long zsA,
    const f16* __restrict__ Bh, const f16* __restrict__ Bl, int ldb, long zsB,
    const float* __restrict__ bias,
    f16* __restrict__ Ch, f16* __restrict__ Cl, float* __restrict__ Cf,
    int ldc, long zsC, int K,
    const float* __restrict__ rowScale,
    const int* __restrict__ task, const float* __restrict__ KQ2,
    float* __restrict__ scores, int expert) {
    __shared__ f16 As[2][128][64];
    __shared__ f16 Bs[2][128][64];
    const int z = blockIdx.z;
    Ah += (long)z * zsA; Al += (long)z * zsA;
    Bh += (long)z * zsB; Bl += (long)z * zsB;
    if (OUTM <= 1) { Ch += (long)z * zsC; Cl += (long)z * zsC; }
    if (OUTM == 2 || OUTM == 3) { Cf += (long)z * zsC; }
    const int tid = threadIdx.x;
    const int l = tid & 63;
    const int w = tid >> 6;
    const int row0 = blockIdx.x * 128;
    const int col0 = blockIdx.y * 128;
    const int wr = (w >> 1) * 64;
    const int wc = (w & 1) * 64;
    const int srow = l >> 3;            // 0..7
    const int scl = l & 7;              // logical 16B chunk
    const int sphys = (scl ^ srow) * 8; // swizzled f16 offset within row

    f32x4 acc[4][4];
#pragma unroll
    for (int mi = 0; mi < 4; ++mi)
#pragma unroll
        for (int ni = 0; ni < 4; ++ni)
#pragma unroll
            for (int j = 0; j < 4; ++j) acc[mi][ni][j] = 0.f;

    for (int k0 = 0; k0 < K; k0 += 64) {
        __syncthreads();
        {
            const f16* pah = Ah + (long)(row0 + w * 32 + srow) * lda + k0 + scl * 8;
            const f16* pal = Al + (long)(row0 + w * 32 + srow) * lda + k0 + scl * 8;
#pragma unroll
            for (int i = 0; i < 4; ++i)
                *(uint4*)&As[0][w * 32 + 8 * i + srow][sphys] = *(const uint4*)(pah + (long)8 * i * lda);
#pragma unroll
            for (int i = 0; i < 4; ++i)
                *(uint4*)&As[1][w * 32 + 8 * i + srow][sphys] = *(const uint4*)(pal + (long)8 * i * lda);
            const f16* pbh = Bh + (long)(col0 + w * 32 + srow) * ldb + k0 + scl * 8;
            const f16* pbl = Bl + (long)(col0 + w * 32 + srow) * ldb + k0 + scl * 8;
#pragma unroll
            for (int i = 0; i < 4; ++i)
                *(uint4*)&Bs[0][w * 32 + 8 * i + srow][sphys] = *(const uint4*)(pbh + (long)8 * i * ldb);
#pragma unroll
            for (int i = 0; i < 4; ++i)
                *(uint4*)&Bs[1][w * 32 + 8 * i + srow][sphys] = *(const uint4*)(pbl + (long)8 * i * ldb);
        }
        __syncthreads();
        const int r16 = l & 15, kg = l >> 4;  // A row / k-group per 16x16x32 layout
#pragma unroll
        for (int ks = 0; ks < 2; ++ks) {
            f16x8 a_h[4], a_l[4], b_h[4], b_l[4];
#pragma unroll
            for (int mi = 0; mi < 4; ++mi) {
                const int r = wr + mi * 16 + r16;
                const int off = ((ks * 4 + kg) ^ (r & 7)) * 8;
                a_h[mi] = *(const f16x8*)&As[0][r][off];
                a_l[mi] = *(const f16x8*)&As[1][r][off];
            }
#pragma unroll
            for (int ni = 0; ni < 4; ++ni) {
                const int c = wc + ni * 16 + r16;
                const int off = ((ks * 4 + kg) ^ (c & 7)) * 8;
                b_h[ni] = *(const f16x8*)&Bs[0][c][off];
                b_l[ni] = *(const f16x8*)&Bs[1][c][off];
            }
#pragma unroll
            for (int mi = 0; mi < 4; ++mi)
#pragma unroll
                for (int ni = 0; ni < 4; ++ni) {
                    acc[mi][ni] = __builtin_amdgcn_mfma_f32_16x16x32_f16(a_h[mi], b_h[ni], acc[mi][ni], 0, 0, 0);
                    acc[mi][ni] = __builtin_amdgcn_mfma_f32_16x16x32_f16(a_h[mi], b_l[ni], acc[mi][ni], 0, 0, 0);
                    acc[mi][ni] = __builtin_amdgcn_mfma_f32_16x16x32_f16(a_l[mi], b_h[ni], acc[mi][ni], 0, 0, 0);
                }
        }
    }
    // epilogue. C layout (m89-verified): col = lane&15, row = (lane>>4)*4 + reg.
    const int lane15 = l & 15;
    const int rsub = (l >> 4) * 4;
    if (OUTM == 4) {
        float bv[4];
#pragma unroll
        for (int ni = 0; ni < 4; ++ni)
            bv[ni] = bias ? bias[col0 + wc + ni * 16 + lane15] : 0.f;
#pragma unroll
        for (int mi = 0; mi < 4; ++mi)
#pragma unroll
            for (int j = 0; j < 4; ++j) {
                const int rowg = row0 + wr + mi * 16 + rsub + j;
                const int t = task[rowg];
                const float* kqr = KQ2 + ((long)t * 16 + expert) * 512;
                float part = 0.f;
#pragma unroll
                for (int ni = 0; ni < 4; ++ni) {
                    const int colg = col0 + wc + ni * 16 + lane15;
                    float v = acc[mi][ni][j] + bv[ni];
                    if (RELU) v = fmaxf(v, 0.f);
                    part += v * kqr[colg];
                }
                // rows are distinct per 16-lane group: reduce over the 16 lanes
#pragma unroll
                for (int d = 1; d < 16; d <<= 1) part += __shfl_xor(part, d);
                if (lane15 == 0) atomicAdd(&scores[rowg * 16 + expert], part);
            }
    } else {
#pragma unroll
        for (int mi = 0; mi < 4; ++mi)
#pragma unroll
            for (int ni = 0; ni < 4; ++ni) {
                const int colg = col0 + wc + ni * 16 + lane15;
                const float bv = bias ? bias[colg] : 0.f;
#pragma unroll
                for (int j = 0; j < 4; ++j) {
                    const int rowg = row0 + wr + mi * 16 + rsub + j;
                    float v = acc[mi][ni][j] + bv;
                    if (RELU) v = fmaxf(v, 0.f);
                    if (OUTM == 0 && rowScale) v *= rowScale[(long)rowg * 16];
                    if (OUTM == 0) {
                        f16 hh, ll; fsplit(v, hh, ll);
                        const long idx = (long)rowg * ldc + colg;
                        Ch[idx] = hh; Cl[idx] = ll;
                    } else if (OUTM == 1) {
                        f16 hh, ll; fsplit(v, hh, ll);
                        const long idx = (long)colg * ldc + rowg;
                        Ch[idx] = hh; Cl[idx] = ll;
                    } else if (OUTM == 2) {
                        Cf[(long)rowg * ldc + colg] = v;
                    } else if (OUTM == 3) {
                        Cf[(long)rowg * ldc + colg] += v;
                    }
                }
            }
    }
}

// --- KQ2[t][e][i] = sum_j Wrows[e*512+i][j] * tq[t][j]  (fp32) -------------
__global__ void kq_kernel(const float* __restrict__ Wrows, const float* __restrict__ tq,
                          float* __restrict__ KQ) {
    __shared__ float qt[10][512];
    const int tid = threadIdx.x;
    const int l = tid & 63, w = tid >> 6;
    const int wave_g = blockIdx.x * 4 + w;
    for (int tile = 0; tile < 5; ++tile) {
        __syncthreads();
        for (int i = tid; i < 10 * 512; i += 256)
            qt[i >> 9][i & 511] = tq[(long)(tile * 10 + (i >> 9)) * 512 + (i & 511)];
        __syncthreads();
        for (int rr = 0; rr < 4; ++rr) {
            const int row = wave_g * 4 + rr;  // 0..8191 = e*512 + i
            const int e = row >> 9, i0 = row & 511;
            float kv[8];
            const float* kp = Wrows + (long)row * 512 + l * 8;
#pragma unroll
            for (int j = 0; j < 8; ++j) kv[j] = kp[j];
#pragma unroll
            for (int tt = 0; tt < 10; ++tt) {
                float s = 0.f;
#pragma unroll
                for (int j = 0; j < 8; ++j) s += kv[j] * qt[tt][l * 8 + j];
#pragma unroll
                for (int d = 1; d < 64; d <<= 1) s += __shfl_xor(s, d);
                if (l == tt) KQ[((long)(tile * 10 + tt) * 16 + e) * 512 + i0] = s;
            }
        }
    }
}

// --- out[e*512+j] = sum_k bvec[e*512+k] * M[e][k][j] -----------------------
__global__ void bias_fold(const float* __restrict__ bvec, const float* __restrict__ M,
                          float* __restrict__ out) {
    const int gid = blockIdx.x * 256 + threadIdx.x;  // 8192
    const int e = gid >> 9, j = gid & 511;
    const float* Me = M + (long)e * 262144;
    const float* be = bvec + e * 512;
    float s = 0.f;
    for (int k = 0; k < 512; ++k) s += be[k] * Me[(long)k * 512 + j];
    out[gid] = s;
}

// --- cb[t][e] = dot(bK[e,:], tq[t,:]) --------------------------------------
__global__ void cb_kernel(const float* __restrict__ bK, const float* __restrict__ tq,
                          float* __restrict__ cb) {
    const int gw = (blockIdx.x * 256 + threadIdx.x) >> 6;  // 0..799
    const int l = threadIdx.x & 63;
    const int t = gw >> 4, e = gw & 15;
    const float* a = bK + e * 512 + l * 8;
    const float* q = tq + (long)t * 512 + l * 8;
    float s = 0.f;
#pragma unroll
    for (int j = 0; j < 8; ++j) s += a[j] * q[j];
#pragma unroll
    for (int d = 1; d < 64; d <<= 1) s += __shfl_xor(s, d);
    if (l == 0) cb[t * 16 + e] = s;
}

// --- scores[b*16+e] = cb[task[b]*16+e]  (init before atomic pass) ----------
__global__ void scores_init(const int* __restrict__ task, const float* __restrict__ cb,
                            float* __restrict__ sc) {
    const int i = blockIdx.x * 256 + threadIdx.x;  // 131072
    sc[i] = cb[task[i >> 4] * 16 + (i & 15)];
}

// --- in-place softmax over E=16 per row ------------------------------------
__global__ void softmax16(float* __restrict__ sc) {
    const int b = blockIdx.x * 256 + threadIdx.x;  // 8192
    float v[16];
    const float4* pp = (const float4*)&sc[b * 16];
#pragma unroll
    for (int qq = 0; qq < 4; ++qq) {
        float4 t = pp[qq];
        v[qq * 4] = t.x; v[qq * 4 + 1] = t.y; v[qq * 4 + 2] = t.z; v[qq * 4 + 3] = t.w;
    }
    float m = v[0];
#pragma unroll
    for (int e = 1; e < 16; ++e) m = fmaxf(m, v[e]);
    float ssum = 0.f;
#pragma unroll
    for (int e = 0; e < 16; ++e) { v[e] = expf(v[e] - m); ssum += v[e]; }
    const float inv = 1.f / ssum;
    float4* o = (float4*)&sc[b * 16];
#pragma unroll
    for (int qq = 0; qq < 4; ++qq) {
        float4 t;
        t.x = v[qq * 4] * inv; t.y = v[qq * 4 + 1] * inv;
        t.z = v[qq * 4 + 2] * inv; t.w = v[qq * 4 + 3] * inv;
        o[qq] = t;
    }
}

// --- towerAcc[b][j] = sum_e w[b][e] * b2V[e][j] ----------------------------
__global__ void wb_init(const float* __restrict__ w, const float* __restrict__ b2V,
                        float* __restrict__ towerAcc) {
    const int b = blockIdx.x;
    const int tid = threadIdx.x;
    float wv[16];
#pragma unroll
    for (int e = 0; e < 16; ++e) wv[e] = w[b * 16 + e];
#pragma unroll
    for (int rep = 0; rep < 2; ++rep) {
        const int j = rep * 256 + tid;
        float s = 0.f;
#pragma unroll
        for (int e = 0; e < 16; ++e) s += wv[e] * b2V[e * 512 + j];
        towerAcc[(long)b * 512 + j] = s;
    }
}

// --- final heads: mu/log_std GEMV (N=32), rsample, tanh-squash, logp -------
__global__ __launch_bounds__(256, 1) void head_kernel(
    const f16* __restrict__ rmh, const f16* __restrict__ rml,
    const f16* __restrict__ rlh, const f16* __restrict__ rll,
    const float* __restrict__ mW2, const float* __restrict__ mb2,
    const float* __restrict__ lW2, const float* __restrict__ lb2,
    const float* __restrict__ eps, float* __restrict__ pi, float* __restrict__ logp) {
    __shared__ float rm[4][512];
    __shared__ float rl[4][512];
    const int tid = threadIdx.x, l = tid & 63, w = tid >> 6;
    const int b = blockIdx.x * 4 + w;  // one wave per row
    const long rb = (long)b * 512 + l * 8;
    {
        f16x8 hh = *(const f16x8*)&rmh[rb];
        f16x8 ll = *(const f16x8*)&rml[rb];
#pragma unroll
        for (int j = 0; j < 8; ++j) rm[w][l * 8 + j] = (float)hh[j] + (float)ll[j];
        f16x8 h2 = *(const f16x8*)&rlh[rb];
        f16x8 l2 = *(const f16x8*)&rll[rb];
#pragma unroll
        for (int j = 0; j < 8; ++j) rl[w][l * 8 + j] = (float)h2[j] + (float)l2[j];
    }
    __syncthreads();
    const int col = l & 31;
    const bool isMu = l < 32;
    const float* W2 = isMu ? mW2 : lW2;
    const float* b2 = isMu ? mb2 : lb2;
    const float* src = isMu ? rm[w] : rl[w];
    float s = b2[col];
#pragma unroll 4
    for (int k = 0; k < 512; ++k) s += src[k] * W2[k * 32 + col];
    const float other = __shfl_xor(s, 32);  // swap mu <-> log_std halves
    if (isMu) {
        const float mu = s;
        float ls = fminf(fmaxf(other, -20.f), 2.f);
        const float e = eps[(long)b * 32 + col];
        const float a = mu + expf(ls) * e;
        float lt = -0.5f * e * e - ls - 0.91893853320467274f;  // -0.5*log(2*pi)
        const float x = -2.f * a;
        const float sp = fmaxf(x, 0.f) + log1pf(expf(-fabsf(x)));
        lt -= 2.f * (0.69314718055994531f - a - sp);
        pi[(long)b * 32 + col] = tanhf(a);
        float r = lt;
#pragma unroll
        for (int d = 1; d < 32; d <<= 1) r += __shfl_xor(r, d);
        if (col == 0) logp[b] = r;
    }
}

// ---------------------------------------------------------------------------
extern "C" void kernel_launch(void* const* d_in, const int* in_sizes, int n_in,
                              void* d_out, int out_size, void* d_ws, size_t ws_size,
                              hipStream_t stream) {
    const float* obs = (const float*)d_in[0];
    const int* task = (const int*)d_in[1];
    const float* eps = (const float*)d_in[2];
    const float* bW1 = (const float*)d_in[3];
    const float* bb1 = (const float*)d_in[4];
    const float* bW2 = (const float*)d_in[5];
    const float* bb2 = (const float*)d_in[6];
    const float* eW1 = (const float*)d_in[7];
    const float* eb1 = (const float*)d_in[8];
    const float* eW2 = (const float*)d_in[9];
    const float* eb2 = (const float*)d_in[10];
    const float* keyM = (const float*)d_in[11];
    const float* valM = (const float*)d_in[12];
    const float* tq = (const float*)d_in[13];
    const float* mW1 = (const float*)d_in[14];
    const float* mb1 = (const float*)d_in[15];
    const float* mW2 = (const float*)d_in[16];
    const float* mb2 = (const float*)d_in[17];
    const float* lW1 = (const float*)d_in[18];
    const float* lb1 = (const float*)d_in[19];
    const float* lW2 = (const float*)d_in[20];
    const float* lb2 = (const float*)d_in[21];
    (void)in_sizes; (void)n_in; (void)out_size; (void)ws_size;

    // ---- workspace map (~121.4 MB, explicit aliasing of dead regions) ----
    const size_t MB = 1u << 20, KB = 1u << 10;
    char* base = (char*)d_ws;
    f16* eW1t_h = (f16*)(base + 0 * MB);   f16* eW1t_l = (f16*)(base + 8 * MB);
    f16* Wv_h   = (f16*)(base + 16 * MB);  f16* Wv_l   = (f16*)(base + 24 * MB);
    f16* eW2s_h = (f16*)(base + 32 * MB);  f16* eW2s_l = (f16*)(base + 40 * MB);
    f16* h2_h   = (f16*)(base + 32 * MB);  f16* h2_l   = (f16*)(base + 40 * MB);  // after folds
    f16* Kt_h   = (f16*)(base + 48 * MB);  f16* Kt_l   = (f16*)(base + 56 * MB);
    f16* t1_h   = (f16*)(base + 48 * MB);  f16* t1_l   = (f16*)(base + 56 * MB);  // after WK fold
    f16* Vt_h   = (f16*)(base + 64 * MB);  f16* Vt_l   = (f16*)(base + 72 * MB);
    f16* Z_h    = (f16*)(base + 64 * MB);  f16* Z_l    = (f16*)(base + 72 * MB);  // after Wv fold
    float* WK       = (float*)(base + 80 * MB);
    float* towerAcc = (float*)(base + 80 * MB);  // after kq_kernel
    f16* twP_h  = (f16*)(base + 96 * MB);  f16* twP_l  = (f16*)(base + 104 * MB);
    f16* obs_h  = (f16*)(base + 112 * MB); f16* obs_l  = (f16*)(base + 114 * MB);
    char* q = base + 116 * MB;
    f16* bW1t_h = (f16*)q; q += 128 * KB;  f16* bW1t_l = (f16*)q; q += 128 * KB;
    f16* bW2t_h = (f16*)q; q += 512 * KB;  f16* bW2t_l = (f16*)q; q += 512 * KB;
    f16* mW1t_h = (f16*)q; q += 512 * KB;  f16* mW1t_l = (f16*)q; q += 512 * KB;
    f16* lW1t_h = (f16*)q; q += 512 * KB;  f16* lW1t_l = (f16*)q; q += 512 * KB;
    float* KQ2    = (float*)q; q += 1600 * KB;   // 50*16*512 f32
    float* scores = (float*)q; q += 512 * KB;    // 8192*16 f32 (becomes w)
    float* bK     = (float*)q; q += 32 * KB;
    float* b2V    = (float*)q; q += 32 * KB;
    float* cb     = (float*)q; q += 16 * KB;

    const long EST = 262144;  // per-expert 512x512 stride

    // ---- 1) splits / transposes ----
    split_pairs<<<1024, 256, 0, stream>>>(obs, obs_h, obs_l, 262144);
    split_pairs<<<4096, 256, 0, stream>>>(eW2, eW2s_h, eW2s_l, 1048576);
    transpose_split<<<dim3(4, 16, 1), 256, 0, stream>>>(bW1, bW1t_h, bW1t_l, 128, 512, 0, 0);
    transpose_split<<<dim3(16, 16, 1), 256, 0, stream>>>(bW2, bW2t_h, bW2t_l, 512, 512, 0, 0);
    transpose_split<<<dim3(16, 16, 1), 256, 0, stream>>>(mW1, mW1t_h, mW1t_l, 512, 512, 0, 0);
    transpose_split<<<dim3(16, 16, 1), 256, 0, stream>>>(lW1, lW1t_h, lW1t_l, 512, 512, 0, 0);
    transpose_split<<<dim3(16, 16, 16), 256, 0, stream>>>(eW1, eW1t_h, eW1t_l, 512, 512, EST, EST);
    transpose_split<<<dim3(16, 16, 16), 256, 0, stream>>>(keyM, Kt_h, Kt_l, 512, 512, EST, EST);
    transpose_split<<<dim3(16, 16, 16), 256, 0, stream>>>(valM, Vt_h, Vt_l, 512, 512, EST, EST);

    // ---- 2) attention folds: WK = eW2@K (f32), Wv = (eW2@V)^T (pairs) ----
    gemm_pair<2, false><<<dim3(4, 4, 16), 256, 0, stream>>>(
        eW2s_h, eW2s_l, 512, EST, Kt_h, Kt_l, 512, EST, nullptr,
        nullptr, nullptr, WK, 512, EST, 512, nullptr, nullptr, nullptr, nullptr, 0);
    gemm_pair<1, false><<<dim3(4, 4, 16), 256, 0, stream>>>(
        eW2s_h, eW2s_l, 512, EST, Vt_h, Vt_l, 512, EST, nullptr,
        Wv_h, Wv_l, nullptr, 512, EST, 512, nullptr, nullptr, nullptr, nullptr, 0);
    kq_kernel<<<512, 256, 0, stream>>>(WK, tq, KQ2);
    bias_fold<<<32, 256, 0, stream>>>(eb2, keyM, bK);
    bias_fold<<<32, 256, 0, stream>>>(eb2, valM, b2V);
    cb_kernel<<<200, 256, 0, stream>>>(bK, tq, cb);

    // ---- 3) backbone ----
    const dim3 gg(64, 4, 1);
    gemm_pair<0, true><<<gg, 256, 0, stream>>>(
        obs_h, obs_l, 128, 0, bW1t_h, bW1t_l, 128, 0, bb1,
        t1_h, t1_l, nullptr, 512, 0, 128, nullptr, nullptr, nullptr, nullptr, 0);
    gemm_pair<0, true><<<gg, 256, 0, stream>>>(
        t1_h, t1_l, 512, 0, bW2t_h, bW2t_l, 512, 0, bb2,
        h2_h, h2_l, nullptr, 512, 0, 512, nullptr, nullptr, nullptr, nullptr, 0);

    // ---- 4) pass A: scores[b,e] = relu(h2@eW1_e+eb1_e) . KQ2[task,e,:] + cb ----
    scores_init<<<512, 256, 0, stream>>>(task, cb, scores);
    for (int e = 0; e < 16; ++e)
        gemm_pair<4, true><<<gg, 256, 0, stream>>>(
            h2_h, h2_l, 512, 0, eW1t_h + (long)e * EST, eW1t_l + (long)e * EST, 512, 0,
            eb1 + e * 512, nullptr, nullptr, nullptr, 0, 0, 512,
            nullptr, task, KQ2, scores, e);
    softmax16<<<32, 256, 0, stream>>>(scores);

    // ---- 5) pass B: towerAcc = sum_e w_e * (t1_e @ W2V_e) + sum_e w_e*b2V_e ----
    wb_init<<<8192, 256, 0, stream>>>(scores, b2V, towerAcc);
    for (int e = 0; e < 16; ++e) {
        gemm_pair<0, true><<<gg, 256, 0, stream>>>(
            h2_h, h2_l, 512, 0, eW1t_h + (long)e * EST, eW1t_l + (long)e * EST, 512, 0,
            eb1 + e * 512, t1_h, t1_l, nullptr, 512, 0, 512,
            scores + e, nullptr, nullptr, nullptr, 0);
        gemm_pair<3, false><<<gg, 256, 0, stream>>>(
            t1_h, t1_l, 512, 0, Wv_h + (long)e * EST, Wv_l + (long)e * EST, 512, 0,
            nullptr, nullptr, nullptr, towerAcc, 512, 0, 512,
            nullptr, nullptr, nullptr, nullptr, 0);
    }

    // ---- 6) heads ----
    split_pairs<<<4096, 256, 0, stream>>>(towerAcc, twP_h, twP_l, 1048576);
    gemm_pair<0, true><<<gg, 256, 0, stream>>>(
        twP_h, twP_l, 512, 0, mW1t_h, mW1t_l, 512, 0, mb1,
        Z_h, Z_l, nullptr, 512, 0, 512, nullptr, nullptr, nullptr, nullptr, 0);
    gemm_pair<0, true><<<gg, 256, 0, stream>>>(
        twP_h, twP_l, 512, 0, lW1t_h, lW1t_l, 512, 0, lb1,
        t1_h, t1_l, nullptr, 512, 0, 512, nullptr, nullptr, nullptr, nullptr, 0);
    head_kernel<<<2048, 256, 0, stream>>>(Z_h, Z_l, t1_h, t1_l, mW2, mb2, lW2, lb2, eps,
                                          (float*)d_out, (float*)d_out + 262144);
}

// Round 3
// 1326.041 us; speedup vs baseline: 1.3549x; 1.3549x over previous
//
#include <hip/hip_runtime.h>
#include <hip/hip_bf16.h>
#include <cstdint>

// ---------------------------------------------------------------------------
// SquashedGaussianMoEActor forward, MI355X (gfx950).
// Split-f16 MFMA (hi/lo pairs, 3x v_mfma_f32_16x16x32_f16) for fp32-quality
// accuracy. Attention folded: score = t1.(eW2@K@q), vals = t1@(eW2@V).
// R3: global_load_lds staging (pre-swizzled source), 64x128 tiles (3 blk/CU),
// passA batched z=16, head GEMV rebuilt (W2T + float4 streams).
// B=8192, OBS=128, H=D=512, E=16, T=50, A=32.
// ---------------------------------------------------------------------------

typedef _Float16 f16;
typedef _Float16 f16x4 __attribute__((ext_vector_type(4)));
typedef _Float16 f16x8 __attribute__((ext_vector_type(8)));
typedef float f32x4 __attribute__((ext_vector_type(4)));

__device__ __forceinline__ void fsplit(float x, f16& h, f16& l) {
    h = (f16)x;
    l = (f16)(x - (float)h);
}

__device__ __forceinline__ void gload16(const void* g, void* s) {
    __builtin_amdgcn_global_load_lds(
        (const __attribute__((address_space(1))) void*)g,
        (__attribute__((address_space(3))) void*)s, 16, 0, 0);
}

// --- elementwise fp32 -> f16 pair split -----------------------------------
__global__ void split_pairs(const float* __restrict__ x, f16* __restrict__ h,
                            f16* __restrict__ l, int n4) {
    int i = blockIdx.x * 256 + threadIdx.x;
    if (i >= n4) return;
    float4 v = ((const float4*)x)[i];
    float a[4] = {v.x, v.y, v.z, v.w};
    f16x4 hh, ll;
#pragma unroll
    for (int j = 0; j < 4; ++j) { f16 hj, lj; fsplit(a[j], hj, lj); hh[j] = hj; ll[j] = lj; }
    *(f16x4*)&h[(long)i * 4] = hh;
    *(f16x4*)&l[(long)i * 4] = ll;
}

// --- transpose [K,N] fp32 -> [N,K] f16 pairs (batched via z) ---------------
__global__ void transpose_split(const float* __restrict__ W, f16* __restrict__ Th,
                                f16* __restrict__ Tl, int K, int N, long ist, long ost) {
    __shared__ float t[32][33];
    const float* Wb = W + (long)blockIdx.z * ist;
    const int k0 = blockIdx.x * 32, n0 = blockIdx.y * 32;
    const int tid = threadIdx.x;
    const int r = tid >> 3, c4 = (tid & 7) * 4;
    float4 v = *(const float4*)&Wb[(long)(k0 + r) * N + n0 + c4];
    t[r][c4] = v.x; t[r][c4 + 1] = v.y; t[r][c4 + 2] = v.z; t[r][c4 + 3] = v.w;
    __syncthreads();
    f16x4 hh, ll;
#pragma unroll
    for (int j = 0; j < 4; ++j) { f16 hj, lj; fsplit(t[c4 + j][r], hj, lj); hh[j] = hj; ll[j] = lj; }
    long ob = (long)blockIdx.z * ost + (long)(n0 + r) * K + k0 + c4;
    *(f16x4*)&Th[ob] = hh;
    *(f16x4*)&Tl[ob] = ll;
}

// --- W2T[half][col][k]: [0]=mW2^T, [1]=lW2^T (f32) -------------------------
__global__ void build_w2t(const float* __restrict__ mW2, const float* __restrict__ lW2,
                          float* __restrict__ W2T) {
    const int i = blockIdx.x * 256 + threadIdx.x;  // 32768
    const int half = i >> 14, col = (i >> 9) & 31, k = i & 511;
    const float* src = half ? lW2 : mW2;
    W2T[i] = src[k * 32 + col];
}

// --- split-f16 GEMM: C = act(A @ B^T_stored + bias) ------------------------
// Tile 64x128, BK=64, 4 waves each owning 32x64 (2x4 frags of 16x16x32).
// Staging via global_load_lds (linear LDS dest, pre-swizzled global source;
// read side applies the same chunk^=row&7 involution).
// OUTM: 0 pair write (+opt rowScale), 1 pair write transposed, 2 f32 write,
//       3 f32 accumulate, 4 score mode (row-dot with KQ2 -> atomicAdd).
template <int OUTM, bool RELU>
__global__ __launch_bounds__(256, 3) void gemm_pair(
    const f16* __restrict__ Ah, const f16* __restrict__ Al, int lda, long zsA,
    const f16* __restrict__ Bh, const f16* __restrict__ Bl, int ldb, long zsB,
    const float* __restrict__ bias, long zsBias,
    f16* __restrict__ Ch, f16* __restrict__ Cl, float* __restrict__ Cf,
    int ldc, long zsC, int K,
    const float* __restrict__ rowScale,
    const int* __restrict__ task, const float* __restrict__ KQ2,
    float* __restrict__ scores) {
    __shared__ f16 As[2][64][64];
    __shared__ f16 Bs[2][128][64];
    const int z = blockIdx.z;
    Ah += (long)z * zsA; Al += (long)z * zsA;
    Bh += (long)z * zsB; Bl += (long)z * zsB;
    if (bias) bias += (long)z * zsBias;
    if (OUTM <= 1) { Ch += (long)z * zsC; Cl += (long)z * zsC; }
    if (OUTM == 2 || OUTM == 3) { Cf += (long)z * zsC; }
    const int tid = threadIdx.x;
    const int l = tid & 63;
    const int w = tid >> 6;
    const int row0 = blockIdx.x * 64;
    const int col0 = blockIdx.y * 128;
    const int wr = (w >> 1) * 32;
    const int wc = (w & 1) * 64;
    const int grow = l >> 3;           // row within 8-row group
    const int gch = (l & 7) ^ grow;    // logical k-chunk this lane fetches

    f32x4 acc[2][4];
#pragma unroll
    for (int mi = 0; mi < 2; ++mi)
#pragma unroll
        for (int ni = 0; ni < 4; ++ni)
#pragma unroll
            for (int j = 0; j < 4; ++j) acc[mi][ni][j] = 0.f;

    for (int k0 = 0; k0 < K; k0 += 64) {
        __syncthreads();
        {
            // A: wave w stages rows [w*16, w*16+16), both planes
            const long ga = (long)(row0 + w * 16 + grow) * lda + k0 + gch * 8;
            gload16(Ah + ga, &As[0][w * 16][0]);
            gload16(Ah + ga + (long)8 * lda, &As[0][w * 16 + 8][0]);
            gload16(Al + ga, &As[1][w * 16][0]);
            gload16(Al + ga + (long)8 * lda, &As[1][w * 16 + 8][0]);
            // B: wave w stages rows [w*32, w*32+32), both planes
            const long gb = (long)(col0 + w * 32 + grow) * ldb + k0 + gch * 8;
            gload16(Bh + gb, &Bs[0][w * 32][0]);
            gload16(Bh + gb + (long)8 * ldb, &Bs[0][w * 32 + 8][0]);
            gload16(Bh + gb + (long)16 * ldb, &Bs[0][w * 32 + 16][0]);
            gload16(Bh + gb + (long)24 * ldb, &Bs[0][w * 32 + 24][0]);
            gload16(Bl + gb, &Bs[1][w * 32][0]);
            gload16(Bl + gb + (long)8 * ldb, &Bs[1][w * 32 + 8][0]);
            gload16(Bl + gb + (long)16 * ldb, &Bs[1][w * 32 + 16][0]);
            gload16(Bl + gb + (long)24 * ldb, &Bs[1][w * 32 + 24][0]);
        }
        __syncthreads();
        const int r16 = l & 15, kg = l >> 4;
#pragma unroll
        for (int ks = 0; ks < 2; ++ks) {
            f16x8 a_h[2], a_l[2], b_h[4], b_l[4];
#pragma unroll
            for (int mi = 0; mi < 2; ++mi) {
                const int r = wr + mi * 16 + r16;
                const int off = ((ks * 4 + kg) ^ (r & 7)) * 8;
                a_h[mi] = *(const f16x8*)&As[0][r][off];
                a_l[mi] = *(const f16x8*)&As[1][r][off];
            }
#pragma unroll
            for (int ni = 0; ni < 4; ++ni) {
                const int c = wc + ni * 16 + r16;
                const int off = ((ks * 4 + kg) ^ (c & 7)) * 8;
                b_h[ni] = *(const f16x8*)&Bs[0][c][off];
                b_l[ni] = *(const f16x8*)&Bs[1][c][off];
            }
#pragma unroll
            for (int mi = 0; mi < 2; ++mi)
#pragma unroll
                for (int ni = 0; ni < 4; ++ni) {
                    acc[mi][ni] = __builtin_amdgcn_mfma_f32_16x16x32_f16(a_h[mi], b_h[ni], acc[mi][ni], 0, 0, 0);
                    acc[mi][ni] = __builtin_amdgcn_mfma_f32_16x16x32_f16(a_h[mi], b_l[ni], acc[mi][ni], 0, 0, 0);
                    acc[mi][ni] = __builtin_amdgcn_mfma_f32_16x16x32_f16(a_l[mi], b_h[ni], acc[mi][ni], 0, 0, 0);
                }
        }
    }
    // epilogue. C layout (m89-verified): col = lane&15, row = (lane>>4)*4 + reg.
    const int lane15 = l & 15;
    const int rsub = (l >> 4) * 4;
    if (OUTM == 4) {
        const int expert = blockIdx.z;
        float bv[4];
#pragma unroll
        for (int ni = 0; ni < 4; ++ni)
            bv[ni] = bias ? bias[col0 + wc + ni * 16 + lane15] : 0.f;
#pragma unroll
        for (int mi = 0; mi < 2; ++mi)
#pragma unroll
            for (int j = 0; j < 4; ++j) {
                const int rowg = row0 + wr + mi * 16 + rsub + j;
                const int t = task[rowg];
                const float* kqr = KQ2 + ((long)t * 16 + expert) * 512;
                float part = 0.f;
#pragma unroll
                for (int ni = 0; ni < 4; ++ni) {
                    const int colg = col0 + wc + ni * 16 + lane15;
                    float v = acc[mi][ni][j] + bv[ni];
                    if (RELU) v = fmaxf(v, 0.f);
                    part += v * kqr[colg];
                }
#pragma unroll
                for (int d = 1; d < 16; d <<= 1) part += __shfl_xor(part, d);
                if (lane15 == 0) atomicAdd(&scores[rowg * 16 + expert], part);
            }
    } else {
#pragma unroll
        for (int mi = 0; mi < 2; ++mi)
#pragma unroll
            for (int ni = 0; ni < 4; ++ni) {
                const int colg = col0 + wc + ni * 16 + lane15;
                const float bv = bias ? bias[colg] : 0.f;
#pragma unroll
                for (int j = 0; j < 4; ++j) {
                    const int rowg = row0 + wr + mi * 16 + rsub + j;
                    float v = acc[mi][ni][j] + bv;
                    if (RELU) v = fmaxf(v, 0.f);
                    if (OUTM == 0 && rowScale) v *= rowScale[(long)rowg * 16];
                    if (OUTM == 0) {
                        f16 hh, ll; fsplit(v, hh, ll);
                        const long idx = (long)rowg * ldc + colg;
                        Ch[idx] = hh; Cl[idx] = ll;
                    } else if (OUTM == 1) {
                        f16 hh, ll; fsplit(v, hh, ll);
                        const long idx = (long)colg * ldc + rowg;
                        Ch[idx] = hh; Cl[idx] = ll;
                    } else if (OUTM == 2) {
                        Cf[(long)rowg * ldc + colg] = v;
                    } else if (OUTM == 3) {
                        Cf[(long)rowg * ldc + colg] += v;
                    }
                }
            }
    }
}

// --- KQ2[t][e][i] = sum_j Wrows[e*512+i][j] * tq[t][j]  (fp32) -------------
__global__ void kq_kernel(const float* __restrict__ Wrows, const float* __restrict__ tq,
                          float* __restrict__ KQ) {
    __shared__ float qt[10][512];
    const int tid = threadIdx.x;
    const int l = tid & 63, w = tid >> 6;
    const int wave_g = blockIdx.x * 4 + w;
    for (int tile = 0; tile < 5; ++tile) {
        __syncthreads();
        for (int i = tid; i < 10 * 512; i += 256)
            qt[i >> 9][i & 511] = tq[(long)(tile * 10 + (i >> 9)) * 512 + (i & 511)];
        __syncthreads();
        for (int rr = 0; rr < 4; ++rr) {
            const int row = wave_g * 4 + rr;  // 0..8191 = e*512 + i
            const int e = row >> 9, i0 = row & 511;
            float kv[8];
            const float* kp = Wrows + (long)row * 512 + l * 8;
#pragma unroll
            for (int j = 0; j < 8; ++j) kv[j] = kp[j];
#pragma unroll
            for (int tt = 0; tt < 10; ++tt) {
                float s = 0.f;
#pragma unroll
                for (int j = 0; j < 8; ++j) s += kv[j] * qt[tt][l * 8 + j];
#pragma unroll
                for (int d = 1; d < 64; d <<= 1) s += __shfl_xor(s, d);
                if (l == tt) KQ[((long)(tile * 10 + tt) * 16 + e) * 512 + i0] = s;
            }
        }
    }
}

// --- out[e*512+j] = sum_k bvec[e*512+k] * M[e][k][j] -----------------------
__global__ void bias_fold(const float* __restrict__ bvec, const float* __restrict__ M,
                          float* __restrict__ out) {
    const int gid = blockIdx.x * 256 + threadIdx.x;  // 8192
    const int e = gid >> 9, j = gid & 511;
    const float* Me = M + (long)e * 262144;
    const float* be = bvec + e * 512;
    float s = 0.f;
    for (int k = 0; k < 512; ++k) s += be[k] * Me[(long)k * 512 + j];
    out[gid] = s;
}

// --- cb[t][e] = dot(bK[e,:], tq[t,:]) --------------------------------------
__global__ void cb_kernel(const float* __restrict__ bK, const float* __restrict__ tq,
                          float* __restrict__ cb) {
    const int gw = (blockIdx.x * 256 + threadIdx.x) >> 6;  // 0..799
    const int l = threadIdx.x & 63;
    const int t = gw >> 4, e = gw & 15;
    const float* a = bK + e * 512 + l * 8;
    const float* q = tq + (long)t * 512 + l * 8;
    float s = 0.f;
#pragma unroll
    for (int j = 0; j < 8; ++j) s += a[j] * q[j];
#pragma unroll
    for (int d = 1; d < 64; d <<= 1) s += __shfl_xor(s, d);
    if (l == 0) cb[t * 16 + e] = s;
}

// --- scores[b*16+e] = cb[task[b]*16+e]  (init before atomic pass) ----------
__global__ void scores_init(const int* __restrict__ task, const float* __restrict__ cb,
                            float* __restrict__ sc) {
    const int i = blockIdx.x * 256 + threadIdx.x;  // 131072
    sc[i] = cb[task[i >> 4] * 16 + (i & 15)];
}

// --- in-place softmax over E=16 per row ------------------------------------
__global__ void softmax16(float* __restrict__ sc) {
    const int b = blockIdx.x * 256 + threadIdx.x;  // 8192
    float v[16];
    const float4* pp = (const float4*)&sc[b * 16];
#pragma unroll
    for (int qq = 0; qq < 4; ++qq) {
        float4 t = pp[qq];
        v[qq * 4] = t.x; v[qq * 4 + 1] = t.y; v[qq * 4 + 2] = t.z; v[qq * 4 + 3] = t.w;
    }
    float m = v[0];
#pragma unroll
    for (int e = 1; e < 16; ++e) m = fmaxf(m, v[e]);
    float ssum = 0.f;
#pragma unroll
    for (int e = 0; e < 16; ++e) { v[e] = expf(v[e] - m); ssum += v[e]; }
    const float inv = 1.f / ssum;
    float4* o = (float4*)&sc[b * 16];
#pragma unroll
    for (int qq = 0; qq < 4; ++qq) {
        float4 t;
        t.x = v[qq * 4] * inv; t.y = v[qq * 4 + 1] * inv;
        t.z = v[qq * 4 + 2] * inv; t.w = v[qq * 4 + 3] * inv;
        o[qq] = t;
    }
}

// --- towerAcc[b][j] = sum_e w[b][e] * b2V[e][j] ----------------------------
__global__ void wb_init(const float* __restrict__ w, const float* __restrict__ b2V,
                        float* __restrict__ towerAcc) {
    const int b = blockIdx.x;
    const int tid = threadIdx.x;
    float wv[16];
#pragma unroll
    for (int e = 0; e < 16; ++e) wv[e] = w[b * 16 + e];
#pragma unroll
    for (int rep = 0; rep < 2; ++rep) {
        const int j = rep * 256 + tid;
        float s = 0.f;
#pragma unroll
        for (int e = 0; e < 16; ++e) s += wv[e] * b2V[e * 512 + j];
        towerAcc[(long)b * 512 + j] = s;
    }
}

// --- final heads v2: GEMV vs W2T (float4 streams), squash, logp ------------
// Rcat: [8192][1024] pairs, cols 0..511 = relu(tower@mW1+mb1), 512..1023 = ls path.
__global__ void head_kernel2(
    const f16* __restrict__ Rh, const f16* __restrict__ Rl,
    const float* __restrict__ W2T,   // [2][32][512]
    const float* __restrict__ mb2, const float* __restrict__ lb2,
    const float* __restrict__ eps, float* __restrict__ pi, float* __restrict__ logp) {
    __shared__ float src[4][1032];
    const int tid = threadIdx.x, l = tid & 63, w = tid >> 6;
    const int b = blockIdx.x * 4 + w;  // one wave per row
    const long rb = (long)b * 1024;
    {
        f16x8 h0 = *(const f16x8*)&Rh[rb + l * 8];
        f16x8 l0 = *(const f16x8*)&Rl[rb + l * 8];
        f16x8 h1 = *(const f16x8*)&Rh[rb + 512 + l * 8];
        f16x8 l1 = *(const f16x8*)&Rl[rb + 512 + l * 8];
#pragma unroll
        for (int j = 0; j < 8; ++j) {
            src[w][l * 8 + j] = (float)h0[j] + (float)l0[j];
            src[w][512 + l * 8 + j] = (float)h1[j] + (float)l1[j];
        }
    }
    __syncthreads();
    const int col = l & 31;
    const int half = l >> 5;  // 0 = mu, 1 = log_std
    const float4* wp = (const float4*)(W2T + ((long)(half * 32 + col)) * 512);
    const float4* sp = (const float4*)(&src[w][half * 512]);
    float a0 = 0.f, a1 = 0.f, a2 = 0.f, a3 = 0.f;
#pragma unroll 8
    for (int k4 = 0; k4 < 128; ++k4) {
        const float4 wv = wp[k4];
        const float4 sv = sp[k4];
        a0 = fmaf(wv.x, sv.x, a0);
        a1 = fmaf(wv.y, sv.y, a1);
        a2 = fmaf(wv.z, sv.z, a2);
        a3 = fmaf(wv.w, sv.w, a3);
    }
    const float* b2 = half ? lb2 : mb2;
    float s = b2[col] + ((a0 + a1) + (a2 + a3));
    const float other = __shfl_xor(s, 32);  // swap mu <-> log_std halves
    if (half == 0) {
        const float mu = s;
        float ls = fminf(fmaxf(other, -20.f), 2.f);
        const float e = eps[(long)b * 32 + col];
        const float a = mu + expf(ls) * e;
        float lt = -0.5f * e * e - ls - 0.91893853320467274f;  // -0.5*log(2*pi)
        const float x = -2.f * a;
        const float sp2 = fmaxf(x, 0.f) + log1pf(expf(-fabsf(x)));
        lt -= 2.f * (0.69314718055994531f - a - sp2);
        pi[(long)b * 32 + col] = tanhf(a);
        float r = lt;
#pragma unroll
        for (int d = 1; d < 32; d <<= 1) r += __shfl_xor(r, d);
        if (col == 0) logp[b] = r;
    }
}

// ---------------------------------------------------------------------------
extern "C" void kernel_launch(void* const* d_in, const int* in_sizes, int n_in,
                              void* d_out, int out_size, void* d_ws, size_t ws_size,
                              hipStream_t stream) {
    const float* obs = (const float*)d_in[0];
    const int* task = (const int*)d_in[1];
    const float* eps = (const float*)d_in[2];
    const float* bW1 = (const float*)d_in[3];
    const float* bb1 = (const float*)d_in[4];
    const float* bW2 = (const float*)d_in[5];
    const float* bb2 = (const float*)d_in[6];
    const float* eW1 = (const float*)d_in[7];
    const float* eb1 = (const float*)d_in[8];
    const float* eW2 = (const float*)d_in[9];
    const float* eb2 = (const float*)d_in[10];
    const float* keyM = (const float*)d_in[11];
    const float* valM = (const float*)d_in[12];
    const float* tq = (const float*)d_in[13];
    const float* mW1 = (const float*)d_in[14];
    const float* mb1 = (const float*)d_in[15];
    const float* mW2 = (const float*)d_in[16];
    const float* mb2 = (const float*)d_in[17];
    const float* lW1 = (const float*)d_in[18];
    const float* lb1 = (const float*)d_in[19];
    const float* lW2 = (const float*)d_in[20];
    const float* lb2 = (const float*)d_in[21];
    (void)in_sizes; (void)n_in; (void)out_size; (void)ws_size;

    // ---- workspace map (~122 MB, explicit aliasing of dead regions) ----
    const size_t MB = 1u << 20, KB = 1u << 10;
    char* base = (char*)d_ws;
    f16* eW1t_h = (f16*)(base + 0 * MB);   f16* eW1t_l = (f16*)(base + 8 * MB);
    f16* Wv_h   = (f16*)(base + 16 * MB);  f16* Wv_l   = (f16*)(base + 24 * MB);
    f16* eW2s_h = (f16*)(base + 32 * MB);  f16* eW2s_l = (f16*)(base + 40 * MB);
    f16* h2_h   = (f16*)(base + 32 * MB);  f16* h2_l   = (f16*)(base + 40 * MB);  // after folds
    f16* Kt_h   = (f16*)(base + 48 * MB);  f16* Kt_l   = (f16*)(base + 56 * MB);
    f16* t1_h   = (f16*)(base + 48 * MB);  f16* t1_l   = (f16*)(base + 56 * MB);  // after WK fold
    f16* Rcat_l = (f16*)(base + 48 * MB);                                         // heads (t1 dead)
    f16* Vt_h   = (f16*)(base + 64 * MB);  f16* Vt_l   = (f16*)(base + 72 * MB);
    f16* Rcat_h = (f16*)(base + 64 * MB);                                         // heads (Vt dead)
    float* WK       = (float*)(base + 80 * MB);
    float* towerAcc = (float*)(base + 80 * MB);  // after kq_kernel
    f16* twP_h  = (f16*)(base + 96 * MB);  f16* twP_l  = (f16*)(base + 104 * MB);
    f16* obs_h  = (f16*)(base + 112 * MB); f16* obs_l  = (f16*)(base + 114 * MB);
    char* q = base + 116 * MB;
    f16* bW1t_h = (f16*)q; q += 128 * KB;  f16* bW1t_l = (f16*)q; q += 128 * KB;
    f16* bW2t_h = (f16*)q; q += 512 * KB;  f16* bW2t_l = (f16*)q; q += 512 * KB;
    f16* mW1t_h = (f16*)q; q += 512 * KB;  f16* mW1t_l = (f16*)q; q += 512 * KB;
    f16* lW1t_h = (f16*)q; q += 512 * KB;  f16* lW1t_l = (f16*)q; q += 512 * KB;
    float* KQ2    = (float*)q; q += 1600 * KB;   // 50*16*512 f32
    float* scores = (float*)q; q += 512 * KB;    // 8192*16 f32 (becomes w)
    float* bK     = (float*)q; q += 32 * KB;
    float* b2V    = (float*)q; q += 32 * KB;
    float* cb     = (float*)q; q += 16 * KB;
    float* W2T    = (float*)q; q += 128 * KB;    // [2][32][512]

    const long EST = 262144;  // per-expert 512x512 stride

    // ---- 1) splits / transposes ----
    split_pairs<<<1024, 256, 0, stream>>>(obs, obs_h, obs_l, 262144);
    split_pairs<<<4096, 256, 0, stream>>>(eW2, eW2s_h, eW2s_l, 1048576);
    transpose_split<<<dim3(4, 16, 1), 256, 0, stream>>>(bW1, bW1t_h, bW1t_l, 128, 512, 0, 0);
    transpose_split<<<dim3(16, 16, 1), 256, 0, stream>>>(bW2, bW2t_h, bW2t_l, 512, 512, 0, 0);
    transpose_split<<<dim3(16, 16, 1), 256, 0, stream>>>(mW1, mW1t_h, mW1t_l, 512, 512, 0, 0);
    transpose_split<<<dim3(16, 16, 1), 256, 0, stream>>>(lW1, lW1t_h, lW1t_l, 512, 512, 0, 0);
    transpose_split<<<dim3(16, 16, 16), 256, 0, stream>>>(eW1, eW1t_h, eW1t_l, 512, 512, EST, EST);
    transpose_split<<<dim3(16, 16, 16), 256, 0, stream>>>(keyM, Kt_h, Kt_l, 512, 512, EST, EST);
    transpose_split<<<dim3(16, 16, 16), 256, 0, stream>>>(valM, Vt_h, Vt_l, 512, 512, EST, EST);
    build_w2t<<<128, 256, 0, stream>>>(mW2, lW2, W2T);

    // ---- 2) attention folds: WK = eW2@K (f32), Wv = (eW2@V)^T (pairs) ----
    gemm_pair<2, false><<<dim3(8, 4, 16), 256, 0, stream>>>(
        eW2s_h, eW2s_l, 512, EST, Kt_h, Kt_l, 512, EST, nullptr, 0,
        nullptr, nullptr, WK, 512, EST, 512, nullptr, nullptr, nullptr, nullptr);
    gemm_pair<1, false><<<dim3(8, 4, 16), 256, 0, stream>>>(
        eW2s_h, eW2s_l, 512, EST, Vt_h, Vt_l, 512, EST, nullptr, 0,
        Wv_h, Wv_l, nullptr, 512, EST, 512, nullptr, nullptr, nullptr, nullptr);
    kq_kernel<<<512, 256, 0, stream>>>(WK, tq, KQ2);
    bias_fold<<<32, 256, 0, stream>>>(eb2, keyM, bK);
    bias_fold<<<32, 256, 0, stream>>>(eb2, valM, b2V);
    cb_kernel<<<200, 256, 0, stream>>>(bK, tq, cb);

    // ---- 3) backbone ----
    const dim3 gg(128, 4, 1);
    gemm_pair<0, true><<<gg, 256, 0, stream>>>(
        obs_h, obs_l, 128, 0, bW1t_h, bW1t_l, 128, 0, bb1, 0,
        t1_h, t1_l, nullptr, 512, 0, 128, nullptr, nullptr, nullptr, nullptr);
    gemm_pair<0, true><<<gg, 256, 0, stream>>>(
        t1_h, t1_l, 512, 0, bW2t_h, bW2t_l, 512, 0, bb2, 0,
        h2_h, h2_l, nullptr, 512, 0, 512, nullptr, nullptr, nullptr, nullptr);

    // ---- 4) pass A (one z=16 dispatch): scores += relu(h2@eW1_e+eb1_e).KQ2 ----
    scores_init<<<512, 256, 0, stream>>>(task, cb, scores);
    gemm_pair<4, true><<<dim3(128, 4, 16), 256, 0, stream>>>(
        h2_h, h2_l, 512, 0, eW1t_h, eW1t_l, 512, EST, eb1, 512,
        nullptr, nullptr, nullptr, 0, 0, 512, nullptr, task, KQ2, scores);
    softmax16<<<32, 256, 0, stream>>>(scores);

    // ---- 5) pass B: towerAcc = sum_e w_e*(t1_e @ W2V_e) + sum_e w_e*b2V_e ----
    wb_init<<<8192, 256, 0, stream>>>(scores, b2V, towerAcc);
    for (int e = 0; e < 16; ++e) {
        gemm_pair<0, true><<<gg, 256, 0, stream>>>(
            h2_h, h2_l, 512, 0, eW1t_h + (long)e * EST, eW1t_l + (long)e * EST, 512, 0,
            eb1 + e * 512, 0, t1_h, t1_l, nullptr, 512, 0, 512,
            scores + e, nullptr, nullptr, nullptr);
        gemm_pair<3, false><<<gg, 256, 0, stream>>>(
            t1_h, t1_l, 512, 0, Wv_h + (long)e * EST, Wv_l + (long)e * EST, 512, 0,
            nullptr, 0, nullptr, nullptr, towerAcc, 512, 0, 512,
            nullptr, nullptr, nullptr, nullptr);
    }

    // ---- 6) heads: layer-1 into Rcat [8192][1024], then fused GEMV+squash ----
    split_pairs<<<4096, 256, 0, stream>>>(towerAcc, twP_h, twP_l, 1048576);
    gemm_pair<0, true><<<gg, 256, 0, stream>>>(
        twP_h, twP_l, 512, 0, mW1t_h, mW1t_l, 512, 0, mb1, 0,
        Rcat_h, Rcat_l, nullptr, 1024, 0, 512, nullptr, nullptr, nullptr, nullptr);
    gemm_pair<0, true><<<gg, 256, 0, stream>>>(
        twP_h, twP_l, 512, 0, lW1t_h, lW1t_l, 512, 0, lb1, 0,
        Rcat_h + 512, Rcat_l + 512, nullptr, 1024, 0, 512, nullptr, nullptr, nullptr, nullptr);
    head_kernel2<<<2048, 256, 0, stream>>>(Rcat_h, Rcat_l, W2T, mb2, lb2, eps,
                                           (float*)d_out, (float*)d_out + 262144);
}

// Round 4
// 868.953 us; speedup vs baseline: 2.0676x; 1.5260x over previous
//
#include <hip/hip_runtime.h>
#include <hip/hip_bf16.h>
#include <cstdint>

// ---------------------------------------------------------------------------
// SquashedGaussianMoEActor forward, MI355X (gfx950).
// Split-f16 MFMA (hi/lo pairs) for fp32-quality accuracy. Attention folded:
// score = t1.(eW2@K@q), vals = t1@(eW2@V). R4: passA writes U = t1 (single
// f16, 128 MB) so passB recompute disappears; mixture is ONE K=8192 GEMM
// (A-single x B-pair). Gated on ws_size >= 251 MB, else R3 recompute path.
// B=8192, OBS=128, H=D=512, E=16, T=50, A=32.
// ---------------------------------------------------------------------------

typedef _Float16 f16;
typedef _Float16 f16x4 __attribute__((ext_vector_type(4)));
typedef _Float16 f16x8 __attribute__((ext_vector_type(8)));
typedef float f32x4 __attribute__((ext_vector_type(4)));

__device__ __forceinline__ void fsplit(float x, f16& h, f16& l) {
    h = (f16)x;
    l = (f16)(x - (float)h);
}

__device__ __forceinline__ void gload16(const void* g, void* s) {
    __builtin_amdgcn_global_load_lds(
        (const __attribute__((address_space(1))) void*)g,
        (__attribute__((address_space(3))) void*)s, 16, 0, 0);
}

// --- elementwise fp32 -> f16 pair split -----------------------------------
__global__ void split_pairs(const float* __restrict__ x, f16* __restrict__ h,
                            f16* __restrict__ l, int n4) {
    int i = blockIdx.x * 256 + threadIdx.x;
    if (i >= n4) return;
    float4 v = ((const float4*)x)[i];
    float a[4] = {v.x, v.y, v.z, v.w};
    f16x4 hh, ll;
#pragma unroll
    for (int j = 0; j < 4; ++j) { f16 hj, lj; fsplit(a[j], hj, lj); hh[j] = hj; ll[j] = lj; }
    *(f16x4*)&h[(long)i * 4] = hh;
    *(f16x4*)&l[(long)i * 4] = ll;
}

// --- transpose [K,N] fp32 -> [N,K] f16 pairs (batched via z) ---------------
__global__ void transpose_split(const float* __restrict__ W, f16* __restrict__ Th,
                                f16* __restrict__ Tl, int K, int N, long ist, long ost) {
    __shared__ float t[32][33];
    const float* Wb = W + (long)blockIdx.z * ist;
    const int k0 = blockIdx.x * 32, n0 = blockIdx.y * 32;
    const int tid = threadIdx.x;
    const int r = tid >> 3, c4 = (tid & 7) * 4;
    float4 v = *(const float4*)&Wb[(long)(k0 + r) * N + n0 + c4];
    t[r][c4] = v.x; t[r][c4 + 1] = v.y; t[r][c4 + 2] = v.z; t[r][c4 + 3] = v.w;
    __syncthreads();
    f16x4 hh, ll;
#pragma unroll
    for (int j = 0; j < 4; ++j) { f16 hj, lj; fsplit(t[c4 + j][r], hj, lj); hh[j] = hj; ll[j] = lj; }
    long ob = (long)blockIdx.z * ost + (long)(n0 + r) * K + k0 + c4;
    *(f16x4*)&Th[ob] = hh;
    *(f16x4*)&Tl[ob] = ll;
}

// --- W2T[half][col][k]: [0]=mW2^T, [1]=lW2^T (f32) -------------------------
__global__ void build_w2t(const float* __restrict__ mW2, const float* __restrict__ lW2,
                          float* __restrict__ W2T) {
    const int i = blockIdx.x * 256 + threadIdx.x;  // 32768
    const int half = i >> 14, col = (i >> 9) & 31, k = i & 511;
    const float* src = half ? lW2 : mW2;
    W2T[i] = src[k * 32 + col];
}

// --- bcat = [mb1 ; lb1] ----------------------------------------------------
__global__ void build_bcat(const float* __restrict__ mb1, const float* __restrict__ lb1,
                           float* __restrict__ bcat) {
    const int i = blockIdx.x * 256 + threadIdx.x;  // 1024
    bcat[i] = (i < 512) ? mb1[i] : lb1[i - 512];
}

// --- split-f16 GEMM: C = act(A @ B^T_stored + bias) ------------------------
// Tile 64x128, BK=64, 4 waves each owning 32x64 (2x4 frags of 16x16x32).
// Staging via global_load_lds (linear LDS dest, pre-swizzled global source;
// read side applies the same chunk^=row&7 involution).
// OUTM: 0 pair write (+opt rowScale), 1 pair write transposed, 2 f32 write,
//       3 f32 accumulate, 4 score mode (row-dot KQ2 -> atomicAdd),
//       5 score mode + write t1 single-f16 to Ch (U buffer).
// ASINGLE: A has hi plane only (2 MFMAs/tile-pair instead of 3, LDS 40 KB).
template <int OUTM, bool RELU, bool ASINGLE>
__global__ __launch_bounds__(256, ASINGLE ? 4 : 3) void gemm_pair(
    const f16* __restrict__ Ah, const f16* __restrict__ Al, int lda, long zsA,
    const f16* __restrict__ Bh, const f16* __restrict__ Bl, int ldb, long zsB,
    const float* __restrict__ bias, long zsBias,
    f16* __restrict__ Ch, f16* __restrict__ Cl, float* __restrict__ Cf,
    int ldc, long zsC, int K,
    const float* __restrict__ rowScale,
    const int* __restrict__ task, const float* __restrict__ KQ2,
    float* __restrict__ scores) {
    __shared__ f16 As[ASINGLE ? 1 : 2][64][64];
    __shared__ f16 Bs[2][128][64];
    const int z = blockIdx.z;
    Ah += (long)z * zsA;
    if constexpr (!ASINGLE) Al += (long)z * zsA;
    Bh += (long)z * zsB; Bl += (long)z * zsB;
    if (bias) bias += (long)z * zsBias;
    if (OUTM <= 1) { Ch += (long)z * zsC; Cl += (long)z * zsC; }
    if (OUTM == 5) { Ch += (long)z * zsC; }
    if (OUTM == 2 || OUTM == 3) { Cf += (long)z * zsC; }
    const int tid = threadIdx.x;
    const int l = tid & 63;
    const int w = tid >> 6;
    const int row0 = blockIdx.x * 64;
    const int col0 = blockIdx.y * 128;
    const int wr = (w >> 1) * 32;
    const int wc = (w & 1) * 64;
    const int grow = l >> 3;           // row within 8-row group
    const int gch = (l & 7) ^ grow;    // logical k-chunk this lane fetches

    f32x4 acc[2][4];
#pragma unroll
    for (int mi = 0; mi < 2; ++mi)
#pragma unroll
        for (int ni = 0; ni < 4; ++ni)
#pragma unroll
            for (int j = 0; j < 4; ++j) acc[mi][ni][j] = 0.f;

    for (int k0 = 0; k0 < K; k0 += 64) {
        __syncthreads();
        {
            // A: wave w stages rows [w*16, w*16+16)
            const long ga = (long)(row0 + w * 16 + grow) * lda + k0 + gch * 8;
            gload16(Ah + ga, &As[0][w * 16][0]);
            gload16(Ah + ga + (long)8 * lda, &As[0][w * 16 + 8][0]);
            if constexpr (!ASINGLE) {
                gload16(Al + ga, &As[1][w * 16][0]);
                gload16(Al + ga + (long)8 * lda, &As[1][w * 16 + 8][0]);
            }
            // B: wave w stages rows [w*32, w*32+32), both planes
            const long gb = (long)(col0 + w * 32 + grow) * ldb + k0 + gch * 8;
            gload16(Bh + gb, &Bs[0][w * 32][0]);
            gload16(Bh + gb + (long)8 * ldb, &Bs[0][w * 32 + 8][0]);
            gload16(Bh + gb + (long)16 * ldb, &Bs[0][w * 32 + 16][0]);
            gload16(Bh + gb + (long)24 * ldb, &Bs[0][w * 32 + 24][0]);
            gload16(Bl + gb, &Bs[1][w * 32][0]);
            gload16(Bl + gb + (long)8 * ldb, &Bs[1][w * 32 + 8][0]);
            gload16(Bl + gb + (long)16 * ldb, &Bs[1][w * 32 + 16][0]);
            gload16(Bl + gb + (long)24 * ldb, &Bs[1][w * 32 + 24][0]);
        }
        __syncthreads();
        const int r16 = l & 15, kg = l >> 4;
#pragma unroll
        for (int ks = 0; ks < 2; ++ks) {
            f16x8 a_h[2], a_l[2], b_h[4], b_l[4];
#pragma unroll
            for (int mi = 0; mi < 2; ++mi) {
                const int r = wr + mi * 16 + r16;
                const int off = ((ks * 4 + kg) ^ (r & 7)) * 8;
                a_h[mi] = *(const f16x8*)&As[0][r][off];
                if constexpr (!ASINGLE) a_l[mi] = *(const f16x8*)&As[1][r][off];
            }
#pragma unroll
            for (int ni = 0; ni < 4; ++ni) {
                const int c = wc + ni * 16 + r16;
                const int off = ((ks * 4 + kg) ^ (c & 7)) * 8;
                b_h[ni] = *(const f16x8*)&Bs[0][c][off];
                b_l[ni] = *(const f16x8*)&Bs[1][c][off];
            }
#pragma unroll
            for (int mi = 0; mi < 2; ++mi)
#pragma unroll
                for (int ni = 0; ni < 4; ++ni) {
                    acc[mi][ni] = __builtin_amdgcn_mfma_f32_16x16x32_f16(a_h[mi], b_h[ni], acc[mi][ni], 0, 0, 0);
                    acc[mi][ni] = __builtin_amdgcn_mfma_f32_16x16x32_f16(a_h[mi], b_l[ni], acc[mi][ni], 0, 0, 0);
                    if constexpr (!ASINGLE)
                        acc[mi][ni] = __builtin_amdgcn_mfma_f32_16x16x32_f16(a_l[mi], b_h[ni], acc[mi][ni], 0, 0, 0);
                }
        }
    }
    // epilogue. C layout (m89-verified): col = lane&15, row = (lane>>4)*4 + reg.
    const int lane15 = l & 15;
    const int rsub = (l >> 4) * 4;
    if (OUTM == 4 || OUTM == 5) {
        const int expert = blockIdx.z;
        float bv[4];
#pragma unroll
        for (int ni = 0; ni < 4; ++ni)
            bv[ni] = bias ? bias[col0 + wc + ni * 16 + lane15] : 0.f;
#pragma unroll
        for (int mi = 0; mi < 2; ++mi)
#pragma unroll
            for (int j = 0; j < 4; ++j) {
                const int rowg = row0 + wr + mi * 16 + rsub + j;
                const int t = task[rowg];
                const float* kqr = KQ2 + ((long)t * 16 + expert) * 512;
                float part = 0.f;
#pragma unroll
                for (int ni = 0; ni < 4; ++ni) {
                    const int colg = col0 + wc + ni * 16 + lane15;
                    float v = acc[mi][ni][j] + bv[ni];
                    if (RELU) v = fmaxf(v, 0.f);
                    if (OUTM == 5) Ch[(long)rowg * ldc + colg] = (f16)v;
                    part += v * kqr[colg];
                }
#pragma unroll
                for (int d = 1; d < 16; d <<= 1) part += __shfl_xor(part, d);
                if (lane15 == 0) atomicAdd(&scores[rowg * 16 + expert], part);
            }
    } else {
#pragma unroll
        for (int mi = 0; mi < 2; ++mi)
#pragma unroll
            for (int ni = 0; ni < 4; ++ni) {
                const int colg = col0 + wc + ni * 16 + lane15;
                const float bv = bias ? bias[colg] : 0.f;
#pragma unroll
                for (int j = 0; j < 4; ++j) {
                    const int rowg = row0 + wr + mi * 16 + rsub + j;
                    float v = acc[mi][ni][j] + bv;
                    if (RELU) v = fmaxf(v, 0.f);
                    if (OUTM == 0 && rowScale) v *= rowScale[(long)rowg * 16];
                    if (OUTM == 0) {
                        f16 hh, ll; fsplit(v, hh, ll);
                        const long idx = (long)rowg * ldc + colg;
                        Ch[idx] = hh; Cl[idx] = ll;
                    } else if (OUTM == 1) {
                        f16 hh, ll; fsplit(v, hh, ll);
                        const long idx = (long)colg * ldc + rowg;
                        Ch[idx] = hh; Cl[idx] = ll;
                    } else if (OUTM == 2) {
                        Cf[(long)rowg * ldc + colg] = v;
                    } else if (OUTM == 3) {
                        Cf[(long)rowg * ldc + colg] += v;
                    }
                }
            }
    }
}

// --- KQ2[t][e][i] = sum_j Wrows[e*512+i][j] * tq[t][j]  (fp32) -------------
__global__ void kq_kernel(const float* __restrict__ Wrows, const float* __restrict__ tq,
                          float* __restrict__ KQ) {
    __shared__ float qt[10][512];
    const int tid = threadIdx.x;
    const int l = tid & 63, w = tid >> 6;
    const int wave_g = blockIdx.x * 4 + w;
    for (int tile = 0; tile < 5; ++tile) {
        __syncthreads();
        for (int i = tid; i < 10 * 512; i += 256)
            qt[i >> 9][i & 511] = tq[(long)(tile * 10 + (i >> 9)) * 512 + (i & 511)];
        __syncthreads();
        for (int rr = 0; rr < 4; ++rr) {
            const int row = wave_g * 4 + rr;  // 0..8191 = e*512 + i
            const int e = row >> 9, i0 = row & 511;
            float kv[8];
            const float* kp = Wrows + (long)row * 512 + l * 8;
#pragma unroll
            for (int j = 0; j < 8; ++j) kv[j] = kp[j];
#pragma unroll
            for (int tt = 0; tt < 10; ++tt) {
                float s = 0.f;
#pragma unroll
                for (int j = 0; j < 8; ++j) s += kv[j] * qt[tt][l * 8 + j];
#pragma unroll
                for (int d = 1; d < 64; d <<= 1) s += __shfl_xor(s, d);
                if (l == tt) KQ[((long)(tile * 10 + tt) * 16 + e) * 512 + i0] = s;
            }
        }
    }
}

// --- out[e*512+j] = sum_k bvec[e*512+k] * M[e][k][j] -----------------------
__global__ void bias_fold(const float* __restrict__ bvec, const float* __restrict__ M,
                          float* __restrict__ out) {
    const int gid = blockIdx.x * 256 + threadIdx.x;  // 8192
    const int e = gid >> 9, j = gid & 511;
    const float* Me = M + (long)e * 262144;
    const float* be = bvec + e * 512;
    float s = 0.f;
    for (int k = 0; k < 512; ++k) s += be[k] * Me[(long)k * 512 + j];
    out[gid] = s;
}

// --- cb[t][e] = dot(bK[e,:], tq[t,:]) --------------------------------------
__global__ void cb_kernel(const float* __restrict__ bK, const float* __restrict__ tq,
                          float* __restrict__ cb) {
    const int gw = (blockIdx.x * 256 + threadIdx.x) >> 6;  // 0..799
    const int l = threadIdx.x & 63;
    const int t = gw >> 4, e = gw & 15;
    const float* a = bK + e * 512 + l * 8;
    const float* q = tq + (long)t * 512 + l * 8;
    float s = 0.f;
#pragma unroll
    for (int j = 0; j < 8; ++j) s += a[j] * q[j];
#pragma unroll
    for (int d = 1; d < 64; d <<= 1) s += __shfl_xor(s, d);
    if (l == 0) cb[t * 16 + e] = s;
}

// --- scores[b*16+e] = cb[task[b]*16+e]  (init before atomic pass) ----------
__global__ void scores_init(const int* __restrict__ task, const float* __restrict__ cb,
                            float* __restrict__ sc) {
    const int i = blockIdx.x * 256 + threadIdx.x;  // 131072
    sc[i] = cb[task[i >> 4] * 16 + (i & 15)];
}

// --- in-place softmax over E=16 per row ------------------------------------
__global__ void softmax16(float* __restrict__ sc) {
    const int b = blockIdx.x * 256 + threadIdx.x;  // 8192
    float v[16];
    const float4* pp = (const float4*)&sc[b * 16];
#pragma unroll
    for (int qq = 0; qq < 4; ++qq) {
        float4 t = pp[qq];
        v[qq * 4] = t.x; v[qq * 4 + 1] = t.y; v[qq * 4 + 2] = t.z; v[qq * 4 + 3] = t.w;
    }
    float m = v[0];
#pragma unroll
    for (int e = 1; e < 16; ++e) m = fmaxf(m, v[e]);
    float ssum = 0.f;
#pragma unroll
    for (int e = 0; e < 16; ++e) { v[e] = expf(v[e] - m); ssum += v[e]; }
    const float inv = 1.f / ssum;
    float4* o = (float4*)&sc[b * 16];
#pragma unroll
    for (int qq = 0; qq < 4; ++qq) {
        float4 t;
        t.x = v[qq * 4] * inv; t.y = v[qq * 4 + 1] * inv;
        t.z = v[qq * 4 + 2] * inv; t.w = v[qq * 4 + 3] * inv;
        o[qq] = t;
    }
}

// --- U[b][e*512+k] *= w[b][e], in place ------------------------------------
__global__ void scale_U(f16* __restrict__ U, const float* __restrict__ w) {
    const long i = (long)blockIdx.x * 256 + threadIdx.x;  // 8M threads
    const long base = i * 8;
    const int b = (int)(base >> 13);
    const int e = (int)((base >> 9) & 15);
    const float s = w[b * 16 + e];
    f16x8 v = *(f16x8*)&U[base];
#pragma unroll
    for (int j = 0; j < 8; ++j) v[j] = (f16)((float)v[j] * s);
    *(f16x8*)&U[base] = v;
}

// --- towerAcc[b][j] = sum_e w[b][e] * b2V[e][j] ----------------------------
__global__ void wb_init(const float* __restrict__ w, const float* __restrict__ b2V,
                        float* __restrict__ towerAcc) {
    const int b = blockIdx.x;
    const int tid = threadIdx.x;
    float wv[16];
#pragma unroll
    for (int e = 0; e < 16; ++e) wv[e] = w[b * 16 + e];
#pragma unroll
    for (int rep = 0; rep < 2; ++rep) {
        const int j = rep * 256 + tid;
        float s = 0.f;
#pragma unroll
        for (int e = 0; e < 16; ++e) s += wv[e] * b2V[e * 512 + j];
        towerAcc[(long)b * 512 + j] = s;
    }
}

// --- final heads: GEMV vs W2T (float4 streams), squash, logp ---------------
// Rcat: [8192][1024] pairs, cols 0..511 = relu(tower@mW1+mb1), 512..1023 = ls.
__global__ void head_kernel2(
    const f16* __restrict__ Rh, const f16* __restrict__ Rl,
    const float* __restrict__ W2T,   // [2][32][512]
    const float* __restrict__ mb2, const float* __restrict__ lb2,
    const float* __restrict__ eps, float* __restrict__ pi, float* __restrict__ logp) {
    __shared__ float src[4][1032];
    const int tid = threadIdx.x, l = tid & 63, w = tid >> 6;
    const int b = blockIdx.x * 4 + w;  // one wave per row
    const long rb = (long)b * 1024;
    {
        f16x8 h0 = *(const f16x8*)&Rh[rb + l * 8];
        f16x8 l0 = *(const f16x8*)&Rl[rb + l * 8];
        f16x8 h1 = *(const f16x8*)&Rh[rb + 512 + l * 8];
        f16x8 l1 = *(const f16x8*)&Rl[rb + 512 + l * 8];
#pragma unroll
        for (int j = 0; j < 8; ++j) {
            src[w][l * 8 + j] = (float)h0[j] + (float)l0[j];
            src[w][512 + l * 8 + j] = (float)h1[j] + (float)l1[j];
        }
    }
    __syncthreads();
    const int col = l & 31;
    const int half = l >> 5;  // 0 = mu, 1 = log_std
    const float4* wp = (const float4*)(W2T + ((long)(half * 32 + col)) * 512);
    const float4* sp = (const float4*)(&src[w][half * 512]);
    float a0 = 0.f, a1 = 0.f, a2 = 0.f, a3 = 0.f;
#pragma unroll 8
    for (int k4 = 0; k4 < 128; ++k4) {
        const float4 wv = wp[k4];
        const float4 sv = sp[k4];
        a0 = fmaf(wv.x, sv.x, a0);
        a1 = fmaf(wv.y, sv.y, a1);
        a2 = fmaf(wv.z, sv.z, a2);
        a3 = fmaf(wv.w, sv.w, a3);
    }
    const float* b2 = half ? lb2 : mb2;
    float s = b2[col] + ((a0 + a1) + (a2 + a3));
    const float other = __shfl_xor(s, 32);  // swap mu <-> log_std halves
    if (half == 0) {
        const float mu = s;
        float ls = fminf(fmaxf(other, -20.f), 2.f);
        const float e = eps[(long)b * 32 + col];
        const float a = mu + expf(ls) * e;
        float lt = -0.5f * e * e - ls - 0.91893853320467274f;  // -0.5*log(2*pi)
        const float x = -2.f * a;
        const float sp2 = fmaxf(x, 0.f) + log1pf(expf(-fabsf(x)));
        lt -= 2.f * (0.69314718055994531f - a - sp2);
        pi[(long)b * 32 + col] = tanhf(a);
        float r = lt;
#pragma unroll
        for (int d = 1; d < 32; d <<= 1) r += __shfl_xor(r, d);
        if (col == 0) logp[b] = r;
    }
}

// ---------------------------------------------------------------------------
extern "C" void kernel_launch(void* const* d_in, const int* in_sizes, int n_in,
                              void* d_out, int out_size, void* d_ws, size_t ws_size,
                              hipStream_t stream) {
    const float* obs = (const float*)d_in[0];
    const int* task = (const int*)d_in[1];
    const float* eps = (const float*)d_in[2];
    const float* bW1 = (const float*)d_in[3];
    const float* bb1 = (const float*)d_in[4];
    const float* bW2 = (const float*)d_in[5];
    const float* bb2 = (const float*)d_in[6];
    const float* eW1 = (const float*)d_in[7];
    const float* eb1 = (const float*)d_in[8];
    const float* eW2 = (const float*)d_in[9];
    const float* eb2 = (const float*)d_in[10];
    const float* keyM = (const float*)d_in[11];
    const float* valM = (const float*)d_in[12];
    const float* tq = (const float*)d_in[13];
    const float* mW1 = (const float*)d_in[14];
    const float* mb1 = (const float*)d_in[15];
    const float* mW2 = (const float*)d_in[16];
    const float* mb2 = (const float*)d_in[17];
    const float* lW1 = (const float*)d_in[18];
    const float* lb1 = (const float*)d_in[19];
    const float* lW2 = (const float*)d_in[20];
    const float* lb2 = (const float*)d_in[21];
    (void)in_sizes; (void)n_in; (void)out_size;

    // ---- workspace map (base 122 MB + optional 128 MB U) ----
    const size_t MB = 1u << 20, KB = 1u << 10;
    char* base = (char*)d_ws;
    f16* eW1t_h = (f16*)(base + 0 * MB);   f16* eW1t_l = (f16*)(base + 8 * MB);
    f16* Wv2_h  = (f16*)(base + 16 * MB);  f16* Wv2_l  = (f16*)(base + 24 * MB);  // [j2][(e,i)]
    f16* eW2s_h = (f16*)(base + 32 * MB);  f16* eW2s_l = (f16*)(base + 40 * MB);
    f16* h2_h   = (f16*)(base + 32 * MB);  f16* h2_l   = (f16*)(base + 40 * MB);  // after folds
    f16* Kt_h   = (f16*)(base + 48 * MB);  f16* Kt_l   = (f16*)(base + 56 * MB);
    f16* t1_h   = (f16*)(base + 48 * MB);  f16* t1_l   = (f16*)(base + 56 * MB);  // after WK fold
    f16* Rcat_l = (f16*)(base + 48 * MB);                                         // heads (t1 dead)
    f16* Vt_h   = (f16*)(base + 64 * MB);  f16* Vt_l   = (f16*)(base + 72 * MB);
    f16* Rcat_h = (f16*)(base + 64 * MB);                                         // heads (Vt dead)
    float* WK       = (float*)(base + 80 * MB);
    float* towerAcc = (float*)(base + 80 * MB);  // after kq_kernel
    f16* twP_h  = (f16*)(base + 96 * MB);  f16* twP_l  = (f16*)(base + 104 * MB);
    f16* obs_h  = (f16*)(base + 112 * MB); f16* obs_l  = (f16*)(base + 114 * MB);
    char* q = base + 116 * MB;
    f16* bW1t_h = (f16*)q; q += 128 * KB;  f16* bW1t_l = (f16*)q; q += 128 * KB;
    f16* bW2t_h = (f16*)q; q += 512 * KB;  f16* bW2t_l = (f16*)q; q += 512 * KB;
    // order m_h, l_h, m_l, l_l so the z=2 head GEMM can stride (zsB = 262144)
    f16* mW1t_h = (f16*)q; q += 512 * KB;
    f16* lW1t_h = (f16*)q; q += 512 * KB;
    f16* mW1t_l = (f16*)q; q += 512 * KB;
    f16* lW1t_l = (f16*)q; q += 512 * KB;
    float* KQ2    = (float*)q; q += 1600 * KB;   // 50*16*512 f32
    float* scores = (float*)q; q += 512 * KB;    // 8192*16 f32 (becomes w)
    float* bK     = (float*)q; q += 32 * KB;
    float* b2V    = (float*)q; q += 32 * KB;
    float* cb     = (float*)q; q += 16 * KB;
    float* W2T    = (float*)q; q += 128 * KB;    // [2][32][512]
    float* bcat   = (float*)q; q += 16 * KB;     // [2][512]
    f16* U = (f16*)(base + 122 * MB);            // [8192][8192] single f16
    const bool BIG = ws_size >= (size_t)251 * MB;

    const long EST = 262144;  // per-expert 512x512 stride

    // ---- 1) splits / transposes ----
    split_pairs<<<1024, 256, 0, stream>>>(obs, obs_h, obs_l, 262144);
    split_pairs<<<4096, 256, 0, stream>>>(eW2, eW2s_h, eW2s_l, 1048576);
    transpose_split<<<dim3(4, 16, 1), 256, 0, stream>>>(bW1, bW1t_h, bW1t_l, 128, 512, 0, 0);
    transpose_split<<<dim3(16, 16, 1), 256, 0, stream>>>(bW2, bW2t_h, bW2t_l, 512, 512, 0, 0);
    transpose_split<<<dim3(16, 16, 1), 256, 0, stream>>>(mW1, mW1t_h, mW1t_l, 512, 512, 0, 0);
    transpose_split<<<dim3(16, 16, 1), 256, 0, stream>>>(lW1, lW1t_h, lW1t_l, 512, 512, 0, 0);
    transpose_split<<<dim3(16, 16, 16), 256, 0, stream>>>(eW1, eW1t_h, eW1t_l, 512, 512, EST, EST);
    transpose_split<<<dim3(16, 16, 16), 256, 0, stream>>>(keyM, Kt_h, Kt_l, 512, 512, EST, EST);
    transpose_split<<<dim3(16, 16, 16), 256, 0, stream>>>(valM, Vt_h, Vt_l, 512, 512, EST, EST);
    build_w2t<<<128, 256, 0, stream>>>(mW2, lW2, W2T);
    build_bcat<<<4, 256, 0, stream>>>(mb1, lb1, bcat);

    // ---- 2) attention folds ----
    // WK = eW2@K (f32, per-expert [i][j2])
    gemm_pair<2, false, false><<<dim3(8, 4, 16), 256, 0, stream>>>(
        eW2s_h, eW2s_l, 512, EST, Kt_h, Kt_l, 512, EST, nullptr, 0,
        nullptr, nullptr, WK, 512, EST, 512, nullptr, nullptr, nullptr, nullptr);
    // Wv2[j2][(e,i)] = (eW2@V)[i][j2]  (pair write transposed, ldc=8192, zsC=512)
    gemm_pair<1, false, false><<<dim3(8, 4, 16), 256, 0, stream>>>(
        eW2s_h, eW2s_l, 512, EST, Vt_h, Vt_l, 512, EST, nullptr, 0,
        Wv2_h, Wv2_l, nullptr, 8192, 512, 512, nullptr, nullptr, nullptr, nullptr);
    kq_kernel<<<512, 256, 0, stream>>>(WK, tq, KQ2);
    bias_fold<<<32, 256, 0, stream>>>(eb2, keyM, bK);
    bias_fold<<<32, 256, 0, stream>>>(eb2, valM, b2V);
    cb_kernel<<<200, 256, 0, stream>>>(bK, tq, cb);

    // ---- 3) backbone ----
    const dim3 gg(128, 4, 1);
    gemm_pair<0, true, false><<<gg, 256, 0, stream>>>(
        obs_h, obs_l, 128, 0, bW1t_h, bW1t_l, 128, 0, bb1, 0,
        t1_h, t1_l, nullptr, 512, 0, 128, nullptr, nullptr, nullptr, nullptr);
    gemm_pair<0, true, false><<<gg, 256, 0, stream>>>(
        t1_h, t1_l, 512, 0, bW2t_h, bW2t_l, 512, 0, bb2, 0,
        h2_h, h2_l, nullptr, 512, 0, 512, nullptr, nullptr, nullptr, nullptr);

    // ---- 4) pass A: scores (+ U when BIG) ----
    scores_init<<<512, 256, 0, stream>>>(task, cb, scores);
    if (BIG) {
        gemm_pair<5, true, false><<<dim3(128, 4, 16), 256, 0, stream>>>(
            h2_h, h2_l, 512, 0, eW1t_h, eW1t_l, 512, EST, eb1, 512,
            U, nullptr, nullptr, 8192, 512, 512, nullptr, task, KQ2, scores);
    } else {
        gemm_pair<4, true, false><<<dim3(128, 4, 16), 256, 0, stream>>>(
            h2_h, h2_l, 512, 0, eW1t_h, eW1t_l, 512, EST, eb1, 512,
            nullptr, nullptr, nullptr, 0, 0, 512, nullptr, task, KQ2, scores);
    }
    softmax16<<<32, 256, 0, stream>>>(scores);

    // ---- 5) tower ----
    wb_init<<<8192, 256, 0, stream>>>(scores, b2V, towerAcc);
    if (BIG) {
        scale_U<<<32768, 256, 0, stream>>>(U, scores);
        // towerAcc += Uw @ Wv2  (one GEMM, K=8192, A-single x B-pair)
        gemm_pair<3, false, true><<<dim3(128, 4, 1), 256, 0, stream>>>(
            U, nullptr, 8192, 0, Wv2_h, Wv2_l, 8192, 0, nullptr, 0,
            nullptr, nullptr, towerAcc, 512, 0, 8192, nullptr, nullptr, nullptr, nullptr);
    } else {
        for (int e = 0; e < 16; ++e) {
            gemm_pair<0, true, false><<<gg, 256, 0, stream>>>(
                h2_h, h2_l, 512, 0, eW1t_h + (long)e * EST, eW1t_l + (long)e * EST, 512, 0,
                eb1 + e * 512, 0, t1_h, t1_l, nullptr, 512, 0, 512,
                scores + e, nullptr, nullptr, nullptr);
            gemm_pair<3, false, false><<<gg, 256, 0, stream>>>(
                t1_h, t1_l, 512, 0, Wv2_h + (long)e * 512, Wv2_l + (long)e * 512, 8192, 0,
                nullptr, 0, nullptr, nullptr, towerAcc, 512, 0, 512,
                nullptr, nullptr, nullptr, nullptr);
        }
    }

    // ---- 6) heads: layer-1 into Rcat [8192][1024] (z=2), fused GEMV+squash ----
    split_pairs<<<4096, 256, 0, stream>>>(towerAcc, twP_h, twP_l, 1048576);
    gemm_pair<0, true, false><<<dim3(128, 4, 2), 256, 0, stream>>>(
        twP_h, twP_l, 512, 0, mW1t_h, mW1t_l, 512, 262144, bcat, 512,
        Rcat_h, Rcat_l, nullptr, 1024, 512, 512, nullptr, nullptr, nullptr, nullptr);
    head_kernel2<<<2048, 256, 0, stream>>>(Rcat_h, Rcat_l, W2T, mb2, lb2, eps,
                                           (float*)d_out, (float*)d_out + 262144);
}